// Round 1
// baseline (341.876 us; speedup 1.0000x reference)
//
#include <hip/hip_runtime.h>
#include <hip/hip_bf16.h>

// Problem: BertCRFTagger — B=32, S=512, H=1024, T=32.
// Pipeline:
//  K1 emis:   logits = hidden@W + b -> log_softmax (logem) and softmax (pem), ws.
//  K2 num:    CRF numerator per batch + seq lengths (from mask).
//  K3 chunk:  per (batch, 16-step chunk) transfer matrix in scaled linear space.
//             Invariant: T[i][j] = log(Pl[i][j]) + Moff_i, row-max(Pl)=1.
//  K4 phase2: per batch, alpha0 composed through 32 chunk matrices; denom;
//             llh = num - denom; out = -mean(llh).

#define Bb 32
#define Ss 512
#define Hh 1024
#define Tt 32
#define NROWS (Bb*Ss)          // 16384
#define NCHUNK 32              // chunks per batch, L=16 steps (t=1..511)
#define CHUNK_L 16

// ---------------- K1: emissions ----------------
// 256 blocks x 256 threads; block handles 64 rows; waves split K (256 h each).
__global__ __launch_bounds__(256) void emis_kernel(
    const float* __restrict__ hidden, const float* __restrict__ W,
    const float* __restrict__ bias, float* __restrict__ logem,
    float* __restrict__ pem) {
  __shared__ __align__(16) float hid[64 * 69];   // 64 rows x 64 h, pad 69 (5l+h banks)
  __shared__ __align__(16) float red[4 * 64 * 33]; // per-wave partials [w][row][t]
  __shared__ float corr[64];

  const int tid = threadIdx.x;
  const int wv = __builtin_amdgcn_readfirstlane(tid >> 6); // wave id, uniform
  const int lane = tid & 63;                                // lane == row
  const int row0 = blockIdx.x * 64;

  float acc[32];
#pragma unroll
  for (int t = 0; t < 32; ++t) acc[t] = 0.f;

  for (int c = 0; c < 16; ++c) {  // 16 chunks of 64 h
    // stage 64 rows x 64 h (16KB), coalesced float4
#pragma unroll
    for (int p = 0; p < 4; ++p) {
      int f = tid + 256 * p;           // 0..1023 float4 slots
      int r = f >> 4, q4 = f & 15;
      const float4 v = *(const float4*)(hidden + (size_t)(row0 + r) * Hh + c * 64 + q4 * 4);
      float* dst = &hid[r * 69 + q4 * 4];
      dst[0] = v.x; dst[1] = v.y; dst[2] = v.z; dst[3] = v.w;
    }
    __syncthreads();
    // wave wv consumes h_local in [16*wv, 16*wv+16)
#pragma unroll
    for (int hh = 0; hh < 16; ++hh) {
      const int h_local = 16 * wv + hh;
      const float hvv = hid[lane * 69 + h_local];
      const float* wrow = W + (size_t)(c * 64 + h_local) * Tt; // uniform -> s_load
#pragma unroll
      for (int t = 0; t < 32; ++t) acc[t] = fmaf(hvv, wrow[t], acc[t]);
    }
    __syncthreads();
  }
  // cross-wave reduction
#pragma unroll
  for (int t = 0; t < 32; ++t) red[(wv * 64 + lane) * 33 + t] = acc[t];
  __syncthreads();
  if (tid < 64) {
    const int r = tid;
    float L[32];
    float mx = -3.0e38f;
#pragma unroll
    for (int t = 0; t < 32; ++t) {
      float v = red[(r)*33 + t] + red[(64 + r) * 33 + t] +
                red[(128 + r) * 33 + t] + red[(192 + r) * 33 + t] + bias[t];
      L[t] = v;
      mx = fmaxf(mx, v);
    }
    float se = 0.f;
#pragma unroll
    for (int t = 0; t < 32; ++t) se += __expf(L[t] - mx);
    corr[r] = mx + __logf(se);
#pragma unroll
    for (int t = 0; t < 32; ++t) red[r * 33 + t] = L[t];
  }
  __syncthreads();
  // coalesced output: 2048 floats per block
#pragma unroll
  for (int p = 0; p < 8; ++p) {
    int e = tid + 256 * p;
    int r = e >> 5, t = e & 31;
    float lg = red[r * 33 + t] - corr[r];
    logem[(size_t)row0 * Tt + e] = lg;
    pem[(size_t)row0 * Tt + e] = __expf(lg);
  }
}

// ---------------- K2: numerator + lengths ----------------
__global__ __launch_bounds__(64) void num_kernel(
    const float* __restrict__ logem, const float* __restrict__ start_trans,
    const float* __restrict__ end_trans, const float* __restrict__ trans,
    const int* __restrict__ tags, const int* __restrict__ mask,
    float* __restrict__ numb, int* __restrict__ lenw) {
  const int b = blockIdx.x;
  const int l = threadIdx.x;
  const int base = b * Ss;
  int lensum = 0;
  float s = 0.f;
#pragma unroll
  for (int k = 0; k < 8; ++k) {
    int ss = l + 64 * k;
    int m = mask[base + ss];
    lensum += m;
    if (m) {
      int tg = tags[base + ss];
      s += logem[(size_t)(base + ss) * Tt + tg];
      if (ss > 0) {
        int tp = tags[base + ss - 1];
        s += trans[tp * Tt + tg];
      }
    }
  }
#pragma unroll
  for (int d = 32; d >= 1; d >>= 1) {
    s += __shfl_xor(s, d);
    lensum += __shfl_xor(lensum, d);
  }
  if (l == 0) {
    int len = lensum;
    int t0 = tags[base];
    int tl = tags[base + len - 1];
    numb[b] = s + start_trans[t0] + end_trans[tl];
    lenw[b] = len;
  }
}

// ---------------- K3: chunk transfer matrices ----------------
// grid 1024 = b (low 5 bits) x chunk c; block 1024 threads = (i=tid>>5, j=tid&31)
__global__ __launch_bounds__(1024) void chunk_kernel(
    const float* __restrict__ pem, const float* __restrict__ trans,
    const int* __restrict__ lenw, float* __restrict__ ecT,
    float* __restrict__ moff) {
  const int b = blockIdx.x & 31;
  const int c = blockIdx.x >> 5;
  const int tid = threadIdx.x;
  const int i = tid >> 5, j = tid & 31;
  __shared__ __align__(16) float Pl[32 * 36];   // row pad 36 (16B aligned rows)
  __shared__ float Em[CHUNK_L * 32];

  // Etr column j in registers
  float etr[32];
#pragma unroll
  for (int k = 0; k < 32; ++k) etr[k] = __expf(trans[k * Tt + j]);

  Pl[i * 36 + j] = (i == j) ? 1.0f : 0.0f;

  const int len = lenw[b];
  const int t0 = 1 + c * CHUNK_L;
  int thi = t0 + CHUNK_L;
  if (thi > Ss) thi = Ss;
  if (thi > len) thi = len;
  const int nst = (thi > t0) ? (thi - t0) : 0;

  if (tid < CHUNK_L * 32) {
    int tt = tid >> 5, jj = tid & 31;
    if (tt < nst) Em[tid] = pem[(size_t)(b * Ss + t0 + tt) * Tt + jj];
  }
  float Moff = 0.f;
  __syncthreads();

  for (int st = 0; st < nst; ++st) {
    float s = 0.f;
#pragma unroll
    for (int k4 = 0; k4 < 8; ++k4) {
      const float4 p4 = *(const float4*)&Pl[i * 36 + k4 * 4];  // broadcast per half-wave
      s = fmaf(p4.x, etr[4 * k4 + 0], s);
      s = fmaf(p4.y, etr[4 * k4 + 1], s);
      s = fmaf(p4.z, etr[4 * k4 + 2], s);
      s = fmaf(p4.w, etr[4 * k4 + 3], s);
    }
    const float w = s * Em[st * 32 + j];
    float m = w;
#pragma unroll
    for (int d = 16; d >= 1; d >>= 1) m = fmaxf(m, __shfl_xor(m, d, 32));
    m = fmaxf(m, 1e-30f);
    Moff += __logf(m);
    const float pn = w * __builtin_amdgcn_rcpf(m);
    __syncthreads();
    Pl[i * 36 + j] = pn;
    __syncthreads();
  }
  // transposed store for phase-2 float4 reads: ecT[b][c][j][i]
  ecT[(((size_t)b * NCHUNK + c) * 32 + j) * 32 + i] = Pl[i * 36 + j];
  if (j == 0) moff[((size_t)b * NCHUNK + c) * 32 + i] = Moff;
}

// ---------------- K4: phase-2 sweep + final reduction ----------------
// single block, 1024 threads = (b=tid>>5, j=tid&31)
__global__ __launch_bounds__(1024) void phase2_kernel(
    const float* __restrict__ logem, const float* __restrict__ start_trans,
    const float* __restrict__ end_trans, const float* __restrict__ ecT,
    const float* __restrict__ moff, const float* __restrict__ numb,
    float* __restrict__ out) {
  const int tid = threadIdx.x;
  const int b = tid >> 5, j = tid & 31;
  __shared__ float qlds[32 * 33];
  __shared__ float llh[32];

  float al0 = start_trans[j] + logem[(size_t)(b * Ss) * Tt + j];
  float m0 = al0;
#pragma unroll
  for (int d = 16; d >= 1; d >>= 1) m0 = fmaxf(m0, __shfl_xor(m0, d, 32));
  float a = __expf(al0 - m0);
  float Mb = m0;
  const float eend = __expf(end_trans[j]);

  for (int c = 0; c < NCHUNK; ++c) {
    float mo = moff[((size_t)b * NCHUNK + c) * 32 + j];  // thread j holds row i=j's offset
    float mom = mo;
#pragma unroll
    for (int d = 16; d >= 1; d >>= 1) mom = fmaxf(mom, __shfl_xor(mom, d, 32));
    float q = a * __expf(mo - mom);
    __syncthreads();
    qlds[b * 33 + j] = q;
    __syncthreads();
    const float* er = &ecT[(((size_t)b * NCHUNK + c) * 32 + j) * 32];
    float s = 0.f;
#pragma unroll
    for (int i4 = 0; i4 < 8; ++i4) {
      const float4 e4 = *(const float4*)(er + i4 * 4);
      s = fmaf(e4.x, qlds[b * 33 + i4 * 4 + 0], s);
      s = fmaf(e4.y, qlds[b * 33 + i4 * 4 + 1], s);
      s = fmaf(e4.z, qlds[b * 33 + i4 * 4 + 2], s);
      s = fmaf(e4.w, qlds[b * 33 + i4 * 4 + 3], s);
    }
    float m = s;
#pragma unroll
    for (int d = 16; d >= 1; d >>= 1) m = fmaxf(m, __shfl_xor(m, d, 32));
    m = fmaxf(m, 1e-30f);
    a = s * __builtin_amdgcn_rcpf(m);
    Mb += mom + __logf(m);
  }
  float z = a * eend;
#pragma unroll
  for (int d = 16; d >= 1; d >>= 1) z += __shfl_xor(z, d, 32);
  if (j == 0) {
    float denom = Mb + __logf(z);
    llh[b] = numb[b] - denom;
  }
  __syncthreads();
  if (tid == 0) {
    float ssum = 0.f;
    for (int bb = 0; bb < 32; ++bb) ssum += llh[bb];
    out[0] = -ssum / 32.0f;
  }
}

extern "C" void kernel_launch(void* const* d_in, const int* in_sizes, int n_in,
                              void* d_out, int out_size, void* d_ws, size_t ws_size,
                              hipStream_t stream) {
  const float* hidden = (const float*)d_in[0];
  const float* W = (const float*)d_in[1];
  const float* bias = (const float*)d_in[2];
  const float* start_trans = (const float*)d_in[3];
  const float* end_trans = (const float*)d_in[4];
  const float* trans = (const float*)d_in[5];
  const int* tags = (const int*)d_in[6];
  const int* mask = (const int*)d_in[7];
  float* out = (float*)d_out;

  float* logem = (float*)d_ws;                       // NROWS*T
  float* pem = logem + (size_t)NROWS * Tt;           // NROWS*T
  float* ecT = pem + (size_t)NROWS * Tt;             // B*NCHUNK*32*32
  float* moff = ecT + (size_t)Bb * NCHUNK * 32 * 32; // B*NCHUNK*32
  float* numb = moff + (size_t)Bb * NCHUNK * 32;     // B
  int* lenw = (int*)(numb + Bb);                     // B

  emis_kernel<<<NROWS / 64, 256, 0, stream>>>(hidden, W, bias, logem, pem);
  num_kernel<<<Bb, 64, 0, stream>>>(logem, start_trans, end_trans, trans, tags,
                                    mask, numb, lenw);
  chunk_kernel<<<Bb * NCHUNK, 1024, 0, stream>>>(pem, trans, lenw, ecT, moff);
  phase2_kernel<<<1, 1024, 0, stream>>>(logem, start_trans, end_trans, ecT, moff,
                                        numb, out);
}

// Round 2
// 230.991 us; speedup vs baseline: 1.4800x; 1.4800x over previous
//
#include <hip/hip_runtime.h>
#include <hip/hip_bf16.h>

// Problem: BertCRFTagger — B=32, S=512, H=1024, T=32.
// Pipeline:
//  K1 emis:   logits = hidden@W + b -> log_softmax (logem) and softmax (pem), ws.
//  K2 num:    CRF numerator per batch + seq lengths (from mask).
//  K3 chunk:  per (batch, 16-step chunk) transfer matrix in scaled linear space.
//             Invariant: T[i][j] = log(Pl[i][j]) + Moff_i, row-max(Pl)=1.
//  K4 phase2: ONE WAVE PER BATCH (grid 32), software-pipelined prefetch of the
//             next chunk matrix; no barriers; atomicAdd finalize into d_out
//             (zeroed by hipMemsetAsync on stream — capture-safe).

#define Bb 32
#define Ss 512
#define Hh 1024
#define Tt 32
#define NROWS (Bb*Ss)          // 16384
#define NCHUNK 32              // chunks per batch, L=16 steps (t=1..511)
#define CHUNK_L 16

// ---------------- K1: emissions ----------------
// 256 blocks x 256 threads; block handles 64 rows; waves split K (256 h each).
__global__ __launch_bounds__(256) void emis_kernel(
    const float* __restrict__ hidden, const float* __restrict__ W,
    const float* __restrict__ bias, float* __restrict__ logem,
    float* __restrict__ pem) {
  __shared__ __align__(16) float hid[64 * 69];   // 64 rows x 64 h, pad 69
  __shared__ __align__(16) float red[4 * 64 * 33]; // per-wave partials [w][row][t]
  __shared__ float corr[64];

  const int tid = threadIdx.x;
  const int wv = __builtin_amdgcn_readfirstlane(tid >> 6); // wave id, uniform
  const int lane = tid & 63;                                // lane == row
  const int row0 = blockIdx.x * 64;

  float acc[32];
#pragma unroll
  for (int t = 0; t < 32; ++t) acc[t] = 0.f;

  for (int c = 0; c < 16; ++c) {  // 16 chunks of 64 h
#pragma unroll
    for (int p = 0; p < 4; ++p) {
      int f = tid + 256 * p;           // 0..1023 float4 slots
      int r = f >> 4, q4 = f & 15;
      const float4 v = *(const float4*)(hidden + (size_t)(row0 + r) * Hh + c * 64 + q4 * 4);
      float* dst = &hid[r * 69 + q4 * 4];
      dst[0] = v.x; dst[1] = v.y; dst[2] = v.z; dst[3] = v.w;
    }
    __syncthreads();
#pragma unroll
    for (int hh = 0; hh < 16; ++hh) {
      const int h_local = 16 * wv + hh;
      const float hvv = hid[lane * 69 + h_local];
      const float* wrow = W + (size_t)(c * 64 + h_local) * Tt; // uniform -> s_load
#pragma unroll
      for (int t = 0; t < 32; ++t) acc[t] = fmaf(hvv, wrow[t], acc[t]);
    }
    __syncthreads();
  }
#pragma unroll
  for (int t = 0; t < 32; ++t) red[(wv * 64 + lane) * 33 + t] = acc[t];
  __syncthreads();
  if (tid < 64) {
    const int r = tid;
    float L[32];
    float mx = -3.0e38f;
#pragma unroll
    for (int t = 0; t < 32; ++t) {
      float v = red[(r)*33 + t] + red[(64 + r) * 33 + t] +
                red[(128 + r) * 33 + t] + red[(192 + r) * 33 + t] + bias[t];
      L[t] = v;
      mx = fmaxf(mx, v);
    }
    float se = 0.f;
#pragma unroll
    for (int t = 0; t < 32; ++t) se += __expf(L[t] - mx);
    corr[r] = mx + __logf(se);
#pragma unroll
    for (int t = 0; t < 32; ++t) red[r * 33 + t] = L[t];
  }
  __syncthreads();
#pragma unroll
  for (int p = 0; p < 8; ++p) {
    int e = tid + 256 * p;
    int r = e >> 5, t = e & 31;
    float lg = red[r * 33 + t] - corr[r];
    logem[(size_t)row0 * Tt + e] = lg;
    pem[(size_t)row0 * Tt + e] = __expf(lg);
  }
}

// ---------------- K2: numerator + lengths ----------------
__global__ __launch_bounds__(64) void num_kernel(
    const float* __restrict__ logem, const float* __restrict__ start_trans,
    const float* __restrict__ end_trans, const float* __restrict__ trans,
    const int* __restrict__ tags, const int* __restrict__ mask,
    float* __restrict__ numb, int* __restrict__ lenw) {
  const int b = blockIdx.x;
  const int l = threadIdx.x;
  const int base = b * Ss;
  int lensum = 0;
  float s = 0.f;
#pragma unroll
  for (int k = 0; k < 8; ++k) {
    int ss = l + 64 * k;
    int m = mask[base + ss];
    lensum += m;
    if (m) {
      int tg = tags[base + ss];
      s += logem[(size_t)(base + ss) * Tt + tg];
      if (ss > 0) {
        int tp = tags[base + ss - 1];
        s += trans[tp * Tt + tg];
      }
    }
  }
#pragma unroll
  for (int d = 32; d >= 1; d >>= 1) {
    s += __shfl_xor(s, d);
    lensum += __shfl_xor(lensum, d);
  }
  if (l == 0) {
    int len = lensum;
    int t0 = tags[base];
    int tl = tags[base + len - 1];
    numb[b] = s + start_trans[t0] + end_trans[tl];
    lenw[b] = len;
  }
}

// ---------------- K3: chunk transfer matrices ----------------
// grid 1024 = b (low 5 bits) x chunk c; block 1024 threads = (i=tid>>5, j=tid&31)
__global__ __launch_bounds__(1024) void chunk_kernel(
    const float* __restrict__ pem, const float* __restrict__ trans,
    const int* __restrict__ lenw, float* __restrict__ ecT,
    float* __restrict__ moff) {
  const int b = blockIdx.x & 31;
  const int c = blockIdx.x >> 5;
  const int tid = threadIdx.x;
  const int i = tid >> 5, j = tid & 31;
  __shared__ __align__(16) float Pl[32 * 36];   // row pad 36 (16B aligned rows)
  __shared__ float Em[CHUNK_L * 32];

  float etr[32];
#pragma unroll
  for (int k = 0; k < 32; ++k) etr[k] = __expf(trans[k * Tt + j]);

  Pl[i * 36 + j] = (i == j) ? 1.0f : 0.0f;

  const int len = lenw[b];
  const int t0 = 1 + c * CHUNK_L;
  int thi = t0 + CHUNK_L;
  if (thi > Ss) thi = Ss;
  if (thi > len) thi = len;
  const int nst = (thi > t0) ? (thi - t0) : 0;

  if (tid < CHUNK_L * 32) {
    int tt = tid >> 5, jj = tid & 31;
    if (tt < nst) Em[tid] = pem[(size_t)(b * Ss + t0 + tt) * Tt + jj];
  }
  float Moff = 0.f;
  __syncthreads();

  for (int st = 0; st < nst; ++st) {
    float s = 0.f;
#pragma unroll
    for (int k4 = 0; k4 < 8; ++k4) {
      const float4 p4 = *(const float4*)&Pl[i * 36 + k4 * 4];
      s = fmaf(p4.x, etr[4 * k4 + 0], s);
      s = fmaf(p4.y, etr[4 * k4 + 1], s);
      s = fmaf(p4.z, etr[4 * k4 + 2], s);
      s = fmaf(p4.w, etr[4 * k4 + 3], s);
    }
    const float w = s * Em[st * 32 + j];
    float m = w;
#pragma unroll
    for (int d = 16; d >= 1; d >>= 1) m = fmaxf(m, __shfl_xor(m, d, 32));
    m = fmaxf(m, 1e-30f);
    Moff += __logf(m);
    const float pn = w * __builtin_amdgcn_rcpf(m);
    __syncthreads();
    Pl[i * 36 + j] = pn;
    __syncthreads();
  }
  // transposed store for phase-2 float4 reads: ecT[b][c][j][i]
  ecT[(((size_t)b * NCHUNK + c) * 32 + j) * 32 + i] = Pl[i * 36 + j];
  if (j == 0) moff[((size_t)b * NCHUNK + c) * 32 + i] = Moff;
}

// ---------------- K4: phase-2 sweep, ONE WAVE PER BATCH ----------------
// grid 32 x block 64. Lanes 32..63 duplicate lanes 0..31 (same addresses,
// same values) — no divergence, coalesced dedup. No __syncthreads needed.
__global__ __launch_bounds__(64) void phase2_kernel(
    const float* __restrict__ logem, const float* __restrict__ start_trans,
    const float* __restrict__ end_trans, const float* __restrict__ ecT,
    const float* __restrict__ moff, const float* __restrict__ numb,
    float* __restrict__ out) {
  const int b = blockIdx.x;
  const int lane = threadIdx.x;
  const int j = lane & 31;
  __shared__ __align__(16) float qlds[32];

  const float* base = ecT + (size_t)b * NCHUNK * 32 * 32;  // [c][j][i]
  const float* mbase = moff + (size_t)b * NCHUNK * 32;     // [c][i]

  // current chunk row j (T[i][j] for i=0..31) + its moff
  float4 M[8], N[8];
  const float* r0 = base + j * 32;
#pragma unroll
  for (int k = 0; k < 8; ++k) M[k] = *(const float4*)(r0 + 4 * k);
  float mo_cur = mbase[j];

  // alpha0 in scaled space
  float al0 = start_trans[j] + logem[(size_t)b * Ss * Tt + j];
  float m0 = al0;
#pragma unroll
  for (int d = 16; d >= 1; d >>= 1) m0 = fmaxf(m0, __shfl_xor(m0, d, 32));
  float a = __expf(al0 - m0);
  float Mb = m0;
  const float eend = __expf(end_trans[j]);

  float mo_next = 0.f;
  for (int c = 0; c < NCHUNK; ++c) {
    // prefetch next chunk (hides L3/HBM latency under compute)
    if (c + 1 < NCHUNK) {
      const float* rn = base + ((c + 1) * 32 + j) * 32;
#pragma unroll
      for (int k = 0; k < 8; ++k) N[k] = *(const float4*)(rn + 4 * k);
      mo_next = mbase[(c + 1) * 32 + j];
    }
    // compute with current chunk
    float mom = mo_cur;
#pragma unroll
    for (int d = 16; d >= 1; d >>= 1) mom = fmaxf(mom, __shfl_xor(mom, d, 32));
    float q = a * __expf(mo_cur - mom);
    if (lane < 32) qlds[j] = q;
    __builtin_amdgcn_s_waitcnt(0);  // lgkmcnt(0): LDS write visible in-wave
    float s = 0.f;
#pragma unroll
    for (int k = 0; k < 8; ++k) {
      const float4 q4 = *(const float4*)(qlds + 4 * k);  // broadcast read
      s = fmaf(q4.x, M[k].x, s);
      s = fmaf(q4.y, M[k].y, s);
      s = fmaf(q4.z, M[k].z, s);
      s = fmaf(q4.w, M[k].w, s);
    }
    float m = s;
#pragma unroll
    for (int d = 16; d >= 1; d >>= 1) m = fmaxf(m, __shfl_xor(m, d, 32));
    m = fmaxf(m, 1e-30f);
    a = s * __builtin_amdgcn_rcpf(m);
    Mb += mom + __logf(m);
#pragma unroll
    for (int k = 0; k < 8; ++k) M[k] = N[k];
    mo_cur = mo_next;
  }
  float z = a * eend;
#pragma unroll
  for (int d = 16; d >= 1; d >>= 1) z += __shfl_xor(z, d, 32);
  if (lane == 0) {
    float denom = Mb + __logf(z);
    float llh = numb[b] - denom;
    atomicAdd(out, -llh * (1.0f / 32.0f));  // device-scope, cross-XCD safe
  }
}

extern "C" void kernel_launch(void* const* d_in, const int* in_sizes, int n_in,
                              void* d_out, int out_size, void* d_ws, size_t ws_size,
                              hipStream_t stream) {
  const float* hidden = (const float*)d_in[0];
  const float* W = (const float*)d_in[1];
  const float* bias = (const float*)d_in[2];
  const float* start_trans = (const float*)d_in[3];
  const float* end_trans = (const float*)d_in[4];
  const float* trans = (const float*)d_in[5];
  const int* tags = (const int*)d_in[6];
  const int* mask = (const int*)d_in[7];
  float* out = (float*)d_out;

  float* logem = (float*)d_ws;                       // NROWS*T
  float* pem = logem + (size_t)NROWS * Tt;           // NROWS*T
  float* ecT = pem + (size_t)NROWS * Tt;             // B*NCHUNK*32*32
  float* moff = ecT + (size_t)Bb * NCHUNK * 32 * 32; // B*NCHUNK*32
  float* numb = moff + (size_t)Bb * NCHUNK * 32;     // B
  int* lenw = (int*)(numb + Bb);                     // B

  hipMemsetAsync(out, 0, sizeof(float), stream);  // capture-safe async memset
  emis_kernel<<<NROWS / 64, 256, 0, stream>>>(hidden, W, bias, logem, pem);
  num_kernel<<<Bb, 64, 0, stream>>>(logem, start_trans, end_trans, trans, tags,
                                    mask, numb, lenw);
  chunk_kernel<<<Bb * NCHUNK, 1024, 0, stream>>>(pem, trans, lenw, ecT, moff);
  phase2_kernel<<<Bb, 64, 0, stream>>>(logem, start_trans, end_trans, ecT, moff,
                                       numb, out);
}